// Round 8
// baseline (2081.500 us; speedup 1.0000x reference)
//
#include <hip/hip_runtime.h>
#include <math.h>

#define BATCH 1024
#define HID 256
#define W3 768
#define SLOT (BATCH * HID)

typedef __bf16 bf16_t;
typedef __bf16 bf16x8 __attribute__((ext_vector_type(8)));
typedef __bf16 bf16x4 __attribute__((ext_vector_type(4)));
typedef float f32x4 __attribute__((ext_vector_type(4)));

__device__ inline bf16x8 cvt8(const float4 a, const float4 b) {
    bf16x8 r;
    r[0] = (bf16_t)a.x; r[1] = (bf16_t)a.y; r[2] = (bf16_t)a.z; r[3] = (bf16_t)a.w;
    r[4] = (bf16_t)b.x; r[5] = (bf16_t)b.y; r[6] = (bf16_t)b.z; r[7] = (bf16_t)b.w;
    return r;
}
__device__ inline bf16x4 cvt4(const float4 a) {
    bf16x4 r;
    r[0] = (bf16_t)a.x; r[1] = (bf16_t)a.y; r[2] = (bf16_t)a.z; r[3] = (bf16_t)a.w;
    return r;
}

// bijective XCD swizzle (m204): hw block s -> work id; XCD(s)=s%8 gets a
// contiguous chunk of work ids, so per-cell operand panels stay in one L2.
__device__ inline int swz_work(int bid, int N) {
    const int xcd = bid & 7, idx = bid >> 3;
    const int q = N >> 3, r = N & 7;
    return (xcd < r ? xcd * (q + 1) : r * (q + 1) + (xcd - r) * q) + idx;
}

// ---------- P0a: Wcpb = bf16(W_cp) ----------
__global__ __launch_bounds__(256) void wcp_conv(
        const float* __restrict__ wcp, bf16_t* __restrict__ wcpb) {
    const size_t n4 = (size_t)81 * HID * W3 / 4;
    size_t i = (size_t)blockIdx.x * 256 + threadIdx.x;
    const size_t nth = (size_t)gridDim.x * 256;
    for (; i < n4; i += nth) {
        const float4 v = *(const float4*)(wcp + i * 4);
        *(bf16x4*)(wcpb + i * 4) = cvt4(v);
    }
}

// ---------- P0b: WhpT[k][m][u] = bf16(W_hp[k][u][m]) ----------
__global__ __launch_bounds__(256) void whp_t_kernel(
        const float* __restrict__ whp, bf16_t* __restrict__ whpT) {
    const int k = blockIdx.z;
    const int m0 = blockIdx.x * 64, u0 = blockIdx.y * 64;
    const int t = threadIdx.x;
    const int tm = t & 63, tg = t >> 6;
    const float* src = whp + (size_t)k * HID * W3;
    bf16_t* dst = whpT + (size_t)k * W3 * HID;
    #pragma unroll
    for (int c = 0; c < 2; ++c) {
        const int ub = u0 + (tg + c * 4) * 8;
        bf16x8 v;
        #pragma unroll
        for (int i = 0; i < 8; ++i)
            v[i] = (bf16_t)src[(size_t)(ub + i) * W3 + m0 + tm];
        *(bf16x8*)(dst + (size_t)(m0 + tm) * HID + ub) = v;
    }
}

// ---------- P1: gvec[k][n4] = Whh[k][n4]·b_hp[k] + b_ih + b_hh ----------
__global__ __launch_bounds__(256) void gvec_kernel(
        const float* __restrict__ Whh, const float* __restrict__ bhp,
        const float* __restrict__ bih, const float* __restrict__ bhh,
        float* __restrict__ gvec) {
    const int k = blockIdx.x, t = threadIdx.x;
    __shared__ float bsm[HID];
    bsm[t] = bhp[(size_t)k * HID + t];
    __syncthreads();
    #pragma unroll
    for (int g = 0; g < 4; ++g) {
        const int n4 = g * HID + t;
        const float* wr = Whh + (size_t)k * 4 * HID * HID + (size_t)n4 * HID;
        float s = 0.f;
        for (int u = 0; u < HID; u += 4) {
            const float4 w = *(const float4*)(wr + u);
            s += w.x * bsm[u] + w.y * bsm[u + 1] + w.z * bsm[u + 2] + w.w * bsm[u + 3];
        }
        gvec[(size_t)k * 1024 + n4] = s + bih[(size_t)k * 1024 + n4]
                                        + bhh[(size_t)k * 1024 + n4];
    }
}

// ---------- P2: CC[k][c][m] = perm(Whh)[c]·WhpT[m]  (LDS-free) ----------
// c = by*128 + g*32 + du  <->  Whh row n4 = g*256 + by*32 + du
__global__ __launch_bounds__(256) void compose_kernel(
        const float* __restrict__ Whh, const bf16_t* __restrict__ WhpT,
        bf16_t* __restrict__ CC) {
    const int work = swz_work(blockIdx.x, gridDim.x);
    const int k = work / 48, inner = work % 48;
    const int mt = inner % 6, by = inner / 6;
    const int m0 = mt * 128;
    const int t = threadIdx.x;
    const int lane = t & 63, wid = t >> 6;
    const int wm = wid & 1, wn = wid >> 1;
    const int ln = lane & 15, lh = lane >> 4;
    const float* abase = Whh + (size_t)k * 1024 * HID;
    const bf16_t* bbase = WhpT + (size_t)k * W3 * HID;
    const float* arow[4];
    #pragma unroll
    for (int mf = 0; mf < 4; ++mf) {
        const int cl = wm * 64 + mf * 16 + ln;
        const int n4 = (cl >> 5) * HID + by * 32 + (cl & 31);
        arow[mf] = abase + (size_t)n4 * HID + lh * 8;
    }
    const bf16_t* brow[4];
    #pragma unroll
    for (int nf = 0; nf < 4; ++nf)
        brow[nf] = bbase + (size_t)(m0 + wn * 64 + nf * 16 + ln) * HID + lh * 8;

    f32x4 acc[4][4] = {};
    #pragma unroll 2
    for (int kb = 0; kb < 8; ++kb) {
        bf16x8 af[4], bfv[4];
        #pragma unroll
        for (int mf = 0; mf < 4; ++mf) {
            const float4 a0 = *(const float4*)(arow[mf] + kb * 32);
            const float4 a1 = *(const float4*)(arow[mf] + kb * 32 + 4);
            af[mf] = cvt8(a0, a1);
        }
        #pragma unroll
        for (int nf = 0; nf < 4; ++nf)
            bfv[nf] = *(const bf16x8*)(brow[nf] + kb * 32);
        #pragma unroll
        for (int mf = 0; mf < 4; ++mf)
            #pragma unroll
            for (int nf = 0; nf < 4; ++nf)
                acc[mf][nf] = __builtin_amdgcn_mfma_f32_16x16x32_bf16(
                    af[mf], bfv[nf], acc[mf][nf], 0, 0, 0);
    }
    bf16_t* outp = CC + (size_t)k * 1024 * W3;
    #pragma unroll
    for (int nf = 0; nf < 4; ++nf) {
        const int m = m0 + wn * 64 + nf * 16 + ln;
        #pragma unroll
        for (int mf = 0; mf < 4; ++mf) {
            const int cb = by * 128 + wm * 64 + mf * 16 + lh * 4;
            #pragma unroll
            for (int r = 0; r < 4; ++r)
                outp[(size_t)(cb + r) * W3 + m] = (bf16_t)acc[mf][nf][r];
        }
    }
}

// ---------- P3: prevgates (fully parallel, LDS-free, thread-major out) ----
__global__ __launch_bounds__(256) void prevgates_kernel(
        const float* __restrict__ gridh, const float* __restrict__ gridc,
        const bf16_t* __restrict__ CC, const bf16_t* __restrict__ Wcpb,
        const float* __restrict__ gvec, const float* __restrict__ Wih,
        const float* __restrict__ bcp, const float* __restrict__ x,
        bf16_t* __restrict__ GP, bf16_t* __restrict__ PP) {
    const int work = swz_work(blockIdx.x, gridDim.x);
    const int k = work >> 6, inner = work & 63;
    const int bx = inner & 7, by = inner >> 3;
    const int t = threadIdx.x;
    const int lane = t & 63, wid = t >> 6;
    const int wm = wid & 1, wn = wid >> 1;
    const int ln = lane & 15, lh = lane >> 4;
    const int b0 = bx * 128, u0 = by * 32;

    const float* hb = gridh + (size_t)k * SLOT;
    const float* cb = gridc + (size_t)k * SLOT;
    const float* ha[4]; const float* ca[4];
    #pragma unroll
    for (int mf = 0; mf < 4; ++mf) {
        const int b = b0 + wm * 64 + mf * 16 + ln;
        ha[mf] = hb + (size_t)b * HID + lh * 8;
        ca[mf] = cb + (size_t)b * HID + lh * 8;
    }
    const bf16_t* ccb = CC + (size_t)k * 1024 * W3;
    const bf16_t* b1[4];
    #pragma unroll
    for (int g = 0; g < 4; ++g)
        b1[g] = ccb + (size_t)(by * 128 + g * 32 + wn * 16 + ln) * W3 + 512 + lh * 8;
    const bf16_t* b2 = Wcpb + (size_t)k * HID * W3
                       + (size_t)(u0 + wn * 16 + ln) * W3 + 512 + lh * 8;

    f32x4 accg[4][4] = {};
    f32x4 accp[4] = {};
    #pragma unroll 2
    for (int kb = 0; kb < 8; ++kb) {
        bf16x8 afh[4], afc[4], bfg[4], bfp;
        #pragma unroll
        for (int mf = 0; mf < 4; ++mf) {
            const float4 h0 = *(const float4*)(ha[mf] + kb * 32);
            const float4 h1 = *(const float4*)(ha[mf] + kb * 32 + 4);
            const float4 c0 = *(const float4*)(ca[mf] + kb * 32);
            const float4 c1 = *(const float4*)(ca[mf] + kb * 32 + 4);
            afh[mf] = cvt8(h0, h1);
            afc[mf] = cvt8(c0, c1);
        }
        #pragma unroll
        for (int g = 0; g < 4; ++g)
            bfg[g] = *(const bf16x8*)(b1[g] + kb * 32);
        bfp = *(const bf16x8*)(b2 + kb * 32);
        #pragma unroll
        for (int mf = 0; mf < 4; ++mf) {
            #pragma unroll
            for (int g = 0; g < 4; ++g)
                accg[mf][g] = __builtin_amdgcn_mfma_f32_16x16x32_bf16(
                    afh[mf], bfg[g], accg[mf][g], 0, 0, 0);
            accp[mf] = __builtin_amdgcn_mfma_f32_16x16x32_bf16(
                afc[mf], bfp, accp[mf], 0, 0, 0);
        }
    }

    const int u = u0 + wn * 16 + ln;
    float wv[4], gv[4];
    #pragma unroll
    for (int g = 0; g < 4; ++g) {
        const int n4 = g * HID + u;
        wv[g] = Wih[(size_t)k * 1024 + n4];
        gv[g] = gvec[(size_t)k * 1024 + n4];
    }
    const float bc = bcp[(size_t)k * HID + u];
    const int blk = by * 8 + bx;
    bf16_t* gpb = GP + (size_t)k * (BATCH * 1024) + (size_t)blk * 16384;
    bf16_t* ppb = PP + (size_t)k * SLOT + (size_t)blk * 4096;
    #pragma unroll
    for (int mf = 0; mf < 4; ++mf) {
        #pragma unroll
        for (int rp = 0; rp < 2; ++rp) {
            bf16x8 v;
            #pragma unroll
            for (int a = 0; a < 2; ++a) {
                const int r = rp * 2 + a;
                const int b = b0 + wm * 64 + mf * 16 + lh * 4 + r;
                const float xv = x[(size_t)b * 81 + k];
                #pragma unroll
                for (int g = 0; g < 4; ++g)
                    v[a * 4 + g] = (bf16_t)(accg[mf][g][r] + gv[g] + xv * wv[g]);
            }
            *(bf16x8*)(gpb + (size_t)(mf * 2 + rp) * 2048 + t * 8) = v;
        }
    }
    #pragma unroll
    for (int j = 0; j < 2; ++j) {
        bf16x8 v;
        #pragma unroll
        for (int h2 = 0; h2 < 2; ++h2) {
            const int mf = j * 2 + h2;
            #pragma unroll
            for (int r = 0; r < 4; ++r)
                v[h2 * 4 + r] = (bf16_t)(accp[mf][r] + bc);
        }
        *(bf16x8*)(ppb + (size_t)j * 2048 + t * 8) = v;
    }
}

// ---------- serial wavefront stage (LDS-free, barrier-free) ----------
struct Stage2Desc {
    const float* hs0; const float* cs0;   // left (ko=0) or null
    const float* hs1; const float* cs1;   // up (ko=256) or null
    const bf16_t* cc; const bf16_t* wcpb;
    const bf16_t* gp; const bf16_t* pp;
    float* gh; float* gc;
};
struct Stage2Args { Stage2Desc d[9]; };

__global__ __launch_bounds__(256) void stage2_kernel(Stage2Args args) {
    const int work = swz_work(blockIdx.x, gridDim.x);
    const int cell = work >> 6, inner = work & 63;
    const Stage2Desc sd = args.d[cell];
    const int bx = inner & 7, by = inner >> 3;
    const int t = threadIdx.x;
    const int lane = t & 63, wid = t >> 6;
    const int wm = wid & 1, wn = wid >> 1;
    const int ln = lane & 15, lh = lane >> 4;
    const int b0 = bx * 128, u0 = by * 32;

    f32x4 accg[4][4] = {};
    f32x4 accp[4] = {};
    const float* hseg[2] = { sd.hs0, sd.hs1 };
    const float* cseg[2] = { sd.cs0, sd.cs1 };

    #pragma unroll
    for (int s = 0; s < 2; ++s) {
        const float* hp = hseg[s];
        if (!hp) continue;
        const float* cp = cseg[s];
        const int ko = s * 256;
        const float* ha[4]; const float* ca[4];
        #pragma unroll
        for (int mf = 0; mf < 4; ++mf) {
            const int b = b0 + wm * 64 + mf * 16 + ln;
            ha[mf] = hp + (size_t)b * HID + lh * 8;
            ca[mf] = cp + (size_t)b * HID + lh * 8;
        }
        const bf16_t* b1[4];
        #pragma unroll
        for (int g = 0; g < 4; ++g)
            b1[g] = sd.cc + (size_t)(by * 128 + g * 32 + wn * 16 + ln) * W3 + ko + lh * 8;
        const bf16_t* b2 = sd.wcpb + (size_t)(u0 + wn * 16 + ln) * W3 + ko + lh * 8;
        #pragma unroll 2
        for (int kb = 0; kb < 8; ++kb) {
            bf16x8 afh[4], afc[4], bfg[4], bfp;
            #pragma unroll
            for (int mf = 0; mf < 4; ++mf) {
                const float4 h0 = *(const float4*)(ha[mf] + kb * 32);
                const float4 h1 = *(const float4*)(ha[mf] + kb * 32 + 4);
                const float4 c0 = *(const float4*)(ca[mf] + kb * 32);
                const float4 c1 = *(const float4*)(ca[mf] + kb * 32 + 4);
                afh[mf] = cvt8(h0, h1);
                afc[mf] = cvt8(c0, c1);
            }
            #pragma unroll
            for (int g = 0; g < 4; ++g)
                bfg[g] = *(const bf16x8*)(b1[g] + kb * 32);
            bfp = *(const bf16x8*)(b2 + kb * 32);
            #pragma unroll
            for (int mf = 0; mf < 4; ++mf) {
                #pragma unroll
                for (int g = 0; g < 4; ++g)
                    accg[mf][g] = __builtin_amdgcn_mfma_f32_16x16x32_bf16(
                        afh[mf], bfg[g], accg[mf][g], 0, 0, 0);
                accp[mf] = __builtin_amdgcn_mfma_f32_16x16x32_bf16(
                    afc[mf], bfp, accp[mf], 0, 0, 0);
            }
        }
    }

    const int u = u0 + wn * 16 + ln;
    const int blk = by * 8 + bx;
    const bf16_t* gpb = sd.gp + (size_t)blk * 16384;
    const bf16_t* ppb = sd.pp + (size_t)blk * 4096;
    float pcv[4][4];
    #pragma unroll
    for (int j = 0; j < 2; ++j) {
        const bf16x8 v = *(const bf16x8*)(ppb + (size_t)j * 2048 + t * 8);
        #pragma unroll
        for (int h2 = 0; h2 < 2; ++h2)
            #pragma unroll
            for (int r = 0; r < 4; ++r)
                pcv[j * 2 + h2][r] = accp[j * 2 + h2][r] + (float)v[h2 * 4 + r];
    }
    #pragma unroll
    for (int mf = 0; mf < 4; ++mf) {
        #pragma unroll
        for (int rp = 0; rp < 2; ++rp) {
            const bf16x8 v = *(const bf16x8*)(gpb + (size_t)(mf * 2 + rp) * 2048 + t * 8);
            #pragma unroll
            for (int a = 0; a < 2; ++a) {
                const int r = rp * 2 + a;
                const int b = b0 + wm * 64 + mf * 16 + lh * 4 + r;
                const float gi = accg[mf][0][r] + (float)v[a * 4 + 0];
                const float gf = accg[mf][1][r] + (float)v[a * 4 + 1];
                const float gg = accg[mf][2][r] + (float)v[a * 4 + 2];
                const float go = accg[mf][3][r] + (float)v[a * 4 + 3];
                const float pc = pcv[mf][r];
                const float i_ = 1.f / (1.f + expf(-gi));
                const float f_ = 1.f / (1.f + expf(-gf));
                const float o_ = 1.f / (1.f + expf(-go));
                const float g_ = tanhf(gg);
                const float cn = f_ * pc + i_ * g_;
                const float hn = o_ * tanhf(cn);
                sd.gh[(size_t)b * HID + u] = hn;
                sd.gc[(size_t)b * HID + u] = cn;
            }
        }
    }
}

__global__ __launch_bounds__(256) void final_kernel(
        const float* __restrict__ gh88, const float* __restrict__ gc88,
        const float* __restrict__ Wout, const float* __restrict__ bout,
        float* __restrict__ out, float* __restrict__ fh, float* __restrict__ fc) {
    const int tid = blockIdx.x * blockDim.x + threadIdx.x;
    const int nth = gridDim.x * blockDim.x;
    for (int idx = tid; idx < BATCH * HID; idx += nth) {
        fh[idx] = gh88[idx];
        fc[idx] = gc88[idx];
    }
    if (tid < BATCH) {
        float s = bout[0];
        for (int k = 0; k < HID; ++k) s += gh88[(size_t)tid * HID + k] * Wout[k];
        s = fmaxf(s, 0.f);
        out[tid] = 1.f / (1.f + expf(-s));
    }
}

// ---------- fallback (small ws): two-phase wavefront ----------
template<bool ATOMIC>
__device__ __forceinline__ void proj_core(
        const float* __restrict__ src, const float* __restrict__ W, int koff,
        const float* __restrict__ bias, float* __restrict__ out,
        bf16_t (*Asm)[40], bf16_t (*Bsm)[40]) {
    const int t = threadIdx.x;
    const int lane = t & 63, wid = t >> 6;
    const int wm = wid & 1, wn = wid >> 1;
    const int ln = lane & 15, lh = lane >> 4;
    const int b0 = blockIdx.x * 128, n0 = blockIdx.y * 128;
    const int sr = t >> 1, sq = (t & 1) * 16;
    const float* arow = src + (size_t)(b0 + sr) * HID + sq;
    const float* wrow = W + (size_t)(n0 + sr) * W3 + koff + sq;
    f32x4 acc[4][4] = {};
    for (int kb = 0; kb < 8; ++kb) {
        const float4 a0 = *(const float4*)(arow + kb * 32);
        const float4 a1 = *(const float4*)(arow + kb * 32 + 4);
        const float4 a2 = *(const float4*)(arow + kb * 32 + 8);
        const float4 a3 = *(const float4*)(arow + kb * 32 + 12);
        const float4 w0 = *(const float4*)(wrow + kb * 32);
        const float4 w1 = *(const float4*)(wrow + kb * 32 + 4);
        const float4 w2 = *(const float4*)(wrow + kb * 32 + 8);
        const float4 w3 = *(const float4*)(wrow + kb * 32 + 12);
        const bf16x8 av0 = cvt8(a0, a1), av1 = cvt8(a2, a3);
        const bf16x8 bv0 = cvt8(w0, w1), bv1 = cvt8(w2, w3);
        __syncthreads();
        *(bf16x8*)&Asm[sr][sq] = av0;
        *(bf16x8*)&Asm[sr][sq + 8] = av1;
        *(bf16x8*)&Bsm[sr][sq] = bv0;
        *(bf16x8*)&Bsm[sr][sq + 8] = bv1;
        __syncthreads();
        bf16x8 af[4], bfv[4];
        #pragma unroll
        for (int mf = 0; mf < 4; ++mf)
            af[mf] = *(const bf16x8*)&Asm[wm * 64 + mf * 16 + ln][lh * 8];
        #pragma unroll
        for (int nf = 0; nf < 4; ++nf)
            bfv[nf] = *(const bf16x8*)&Bsm[wn * 64 + nf * 16 + ln][lh * 8];
        #pragma unroll
        for (int mf = 0; mf < 4; ++mf)
            #pragma unroll
            for (int nf = 0; nf < 4; ++nf)
                acc[mf][nf] = __builtin_amdgcn_mfma_f32_16x16x32_bf16(
                    af[mf], bfv[nf], acc[mf][nf], 0, 0, 0);
    }
    #pragma unroll
    for (int nf = 0; nf < 4; ++nf) {
        const int n = n0 + wn * 64 + nf * 16 + ln;
        const float bn = ATOMIC ? 0.f : bias[n];
        #pragma unroll
        for (int mf = 0; mf < 4; ++mf)
            #pragma unroll
            for (int r = 0; r < 4; ++r) {
                const int b = b0 + wm * 64 + mf * 16 + lh * 4 + r;
                if (ATOMIC)
                    unsafeAtomicAdd(out + (size_t)b * HID + n, acc[mf][nf][r]);
                else
                    out[(size_t)b * HID + n] = acc[mf][nf][r] + bn;
            }
    }
}

struct SegDesc { const float* src; const float* W; const float* bias; float* out; int koff; };
struct SegArgs { SegDesc d[36]; };

__global__ __launch_bounds__(256) void projseg_kernel(SegArgs a) {
    __shared__ bf16_t As[128][40];
    __shared__ bf16_t Bs[128][40];
    const SegDesc d = a.d[blockIdx.z];
    if (d.bias) proj_core<false>(d.src, d.W, d.koff, d.bias, d.out, As, Bs);
    else        proj_core<true>(d.src, d.W, d.koff, nullptr, d.out, As, Bs);
}

struct CellDesc {
    const float* ph; const float* pc;
    const float* Whh; const float* Wih; const float* bih; const float* bhh;
    const float* xcol;
    float* gh; float* gc;
};
struct CellBatchArgs { CellDesc d[9]; };

__global__ __launch_bounds__(256) void cell_kernel(CellBatchArgs args) {
    const CellDesc cd = args.d[blockIdx.z];
    __shared__ bf16_t Psm[128][40];
    __shared__ bf16_t Wsm[128][40];
    const int t = threadIdx.x;
    const int lane = t & 63, wid = t >> 6;
    const int wm = wid & 1, wn = wid >> 1;
    const int ln = lane & 15, lh = lane >> 4;
    const int b0 = blockIdx.x * 128;
    const int u0 = blockIdx.y * 32;
    const int sr = t >> 1, sq = (t & 1) * 16;
    const float* prow = cd.ph + (size_t)(b0 + sr) * HID + sq;
    const int cg = sr >> 5, cdu = sr & 31;
    const float* wrow = cd.Whh + (size_t)(cg * HID + u0 + cdu) * HID + sq;
    f32x4 acc[4][4] = {};
    for (int kb = 0; kb < 8; ++kb) {
        const float4 p0 = *(const float4*)(prow + kb * 32);
        const float4 p1 = *(const float4*)(prow + kb * 32 + 4);
        const float4 p2 = *(const float4*)(prow + kb * 32 + 8);
        const float4 p3 = *(const float4*)(prow + kb * 32 + 12);
        const float4 w0 = *(const float4*)(wrow + kb * 32);
        const float4 w1 = *(const float4*)(wrow + kb * 32 + 4);
        const float4 w2 = *(const float4*)(wrow + kb * 32 + 8);
        const float4 w3 = *(const float4*)(wrow + kb * 32 + 12);
        const bf16x8 pv0 = cvt8(p0, p1), pv1 = cvt8(p2, p3);
        const bf16x8 wv0 = cvt8(w0, w1), wv1 = cvt8(w2, w3);
        __syncthreads();
        *(bf16x8*)&Psm[sr][sq] = pv0;
        *(bf16x8*)&Psm[sr][sq + 8] = pv1;
        *(bf16x8*)&Wsm[sr][sq] = wv0;
        *(bf16x8*)&Wsm[sr][sq + 8] = wv1;
        __syncthreads();
        bf16x8 af[4], bfr[4];
        #pragma unroll
        for (int mf = 0; mf < 4; ++mf)
            af[mf] = *(const bf16x8*)&Psm[wm * 64 + mf * 16 + ln][lh * 8];
        #pragma unroll
        for (int g = 0; g < 4; ++g)
            bfr[g] = *(const bf16x8*)&Wsm[g * 32 + wn * 16 + ln][lh * 8];
        #pragma unroll
        for (int mf = 0; mf < 4; ++mf)
            #pragma unroll
            for (int g = 0; g < 4; ++g)
                acc[mf][g] = __builtin_amdgcn_mfma_f32_16x16x32_bf16(
                    af[mf], bfr[g], acc[mf][g], 0, 0, 0);
    }
    const int u = u0 + wn * 16 + ln;
    float wih[4], bsum[4];
    #pragma unroll
    for (int g = 0; g < 4; ++g) {
        const int n = g * HID + u;
        wih[g] = cd.Wih[n];
        bsum[g] = cd.bih[n] + cd.bhh[n];
    }
    #pragma unroll
    for (int mf = 0; mf < 4; ++mf)
        #pragma unroll
        for (int r = 0; r < 4; ++r) {
            const int b = b0 + wm * 64 + mf * 16 + lh * 4 + r;
            const float xv = cd.xcol[(size_t)b * 81];
            const float gi = acc[mf][0][r] + xv * wih[0] + bsum[0];
            const float gf = acc[mf][1][r] + xv * wih[1] + bsum[1];
            const float gg = acc[mf][2][r] + xv * wih[2] + bsum[2];
            const float go = acc[mf][3][r] + xv * wih[3] + bsum[3];
            const float i_ = 1.f / (1.f + expf(-gi));
            const float f_ = 1.f / (1.f + expf(-gf));
            const float o_ = 1.f / (1.f + expf(-go));
            const float g_ = tanhf(gg);
            const float c0 = cd.pc[(size_t)b * HID + u];
            const float cn = f_ * c0 + i_ * g_;
            const float hn = o_ * tanhf(cn);
            cd.gh[(size_t)b * HID + u] = hn;
            cd.gc[(size_t)b * HID + u] = cn;
        }
}

extern "C" void kernel_launch(void* const* d_in, const int* in_sizes, int n_in,
                              void* d_out, int out_size, void* d_ws, size_t ws_size,
                              hipStream_t stream) {
    const float* x      = (const float*)d_in[0];
    const float* h_ext  = (const float*)d_in[1];
    const float* c_ext  = (const float*)d_in[2];
    const float* grid_h = (const float*)d_in[3];
    const float* grid_c = (const float*)d_in[4];
    const float* W_hp   = (const float*)d_in[5];
    const float* b_hp   = (const float*)d_in[6];
    const float* W_cp   = (const float*)d_in[7];
    const float* b_cp   = (const float*)d_in[8];
    const float* W_ih   = (const float*)d_in[9];
    const float* W_hh   = (const float*)d_in[10];
    const float* b_ih   = (const float*)d_in[11];
    const float* b_hh   = (const float*)d_in[12];
    const float* W_out  = (const float*)d_in[13];
    const float* b_out  = (const float*)d_in[14];

    float* out = (float*)d_out;
    float* fh  = out + BATCH * 1;
    float* fc  = fh + SLOT;
    float* gh  = fc + SLOT;
    float* gc  = gh + (size_t)81 * SLOT;

    const size_t wt_b  = (size_t)81 * W3 * HID * 2;     //  31,850,496
    const size_t wcp_b = (size_t)81 * HID * W3 * 2;     //  31,850,496
    const size_t cc_b  = (size_t)81 * 1024 * W3 * 2;    // 127,401,984
    const size_t gp_b  = (size_t)81 * BATCH * 1024 * 2; // 169,869,312
    const size_t pp_b  = (size_t)81 * SLOT * 2;         //  42,467,328
    const size_t gv_b  = (size_t)81 * 1024 * 4;         //     331,776
    const size_t need = wt_b + wcp_b + cc_b + gp_b + pp_b + gv_b;

    if (ws_size >= need) {
        char* p = (char*)d_ws;
        bf16_t* WhpT = (bf16_t*)p; p += wt_b;
        bf16_t* Wcpb = (bf16_t*)p; p += wcp_b;
        bf16_t* CC   = (bf16_t*)p; p += cc_b;
        bf16_t* GP   = (bf16_t*)p; p += gp_b;
        bf16_t* PP   = (bf16_t*)p; p += pp_b;
        float*  gvec = (float*)p;

        wcp_conv<<<dim3(2048), 256, 0, stream>>>(W_cp, Wcpb);
        whp_t_kernel<<<dim3(12, 4, 81), 256, 0, stream>>>(W_hp, WhpT);
        gvec_kernel<<<dim3(81), 256, 0, stream>>>(W_hh, b_hp, b_ih, b_hh, gvec);
        compose_kernel<<<dim3(81 * 48), 256, 0, stream>>>(W_hh, WhpT, CC);
        prevgates_kernel<<<dim3(81 * 64), 256, 0, stream>>>(
            grid_h, grid_c, CC, Wcpb, gvec, W_ih, b_cp, x, GP, PP);

        for (int d = 0; d <= 16; ++d) {
            const int i_lo = d > 8 ? d - 8 : 0;
            const int i_hi = d < 8 ? d : 8;
            const int nc = i_hi - i_lo + 1;
            Stage2Args sa{};
            for (int s = 0; s < nc; ++s) {
                const int i = i_lo + s, j = d - i;
                const int k = i * 9 + j;
                const float *hl = nullptr, *cl = nullptr, *hu = nullptr, *cu = nullptr;
                if (i == 0 && j == 0)      { hl = h_ext; cl = c_ext; }
                else if (j > 0)            { hl = gh + (size_t)(k - 1) * SLOT;
                                             cl = gc + (size_t)(k - 1) * SLOT; }
                if (i > 0)                 { hu = gh + (size_t)(k - 9) * SLOT;
                                             cu = gc + (size_t)(k - 9) * SLOT; }
                sa.d[s] = { hl, cl, hu, cu,
                            CC + (size_t)k * 1024 * W3,
                            Wcpb + (size_t)k * HID * W3,
                            GP + (size_t)k * BATCH * 1024,
                            PP + (size_t)k * SLOT,
                            gh + (size_t)k * SLOT, gc + (size_t)k * SLOT };
            }
            stage2_kernel<<<dim3(nc * 64), 256, 0, stream>>>(sa);
        }
    } else {
        // fallback: two-phase wavefront with 18 rotating slots (needs 18.9 MB)
        float* ws = (float*)d_ws;
        for (int d = 0; d <= 16; ++d) {
            const int i_lo = d > 8 ? d - 8 : 0;
            const int i_hi = d < 8 ? d : 8;
            const int nc = i_hi - i_lo + 1;
            SegArgs base{}, inc{};
            CellBatchArgs ca{};
            int nb = 0, ni = 0;
            for (int s = 0; s < nc; ++s) {
                const int i = i_lo + s, j = d - i;
                const int k = i * 9 + j;
                float* oh = ws + (size_t)(2 * s) * SLOT;
                float* oc = oh + SLOT;
                const float* Wh = W_hp + (size_t)k * HID * W3;
                const float* Wc = W_cp + (size_t)k * HID * W3;
                base.d[nb++] = { grid_h + (size_t)k * SLOT, Wh, b_hp + (size_t)k * HID, oh, 512 };
                base.d[nb++] = { grid_c + (size_t)k * SLOT, Wc, b_cp + (size_t)k * HID, oc, 512 };
                if (i == 0 && j == 0) {
                    inc.d[ni++] = { h_ext, Wh, nullptr, oh, 0 };
                    inc.d[ni++] = { c_ext, Wc, nullptr, oc, 0 };
                } else if (j > 0) {
                    inc.d[ni++] = { gh + (size_t)(k - 1) * SLOT, Wh, nullptr, oh, 0 };
                    inc.d[ni++] = { gc + (size_t)(k - 1) * SLOT, Wc, nullptr, oc, 0 };
                }
                if (i > 0) {
                    inc.d[ni++] = { gh + (size_t)(k - 9) * SLOT, Wh, nullptr, oh, 256 };
                    inc.d[ni++] = { gc + (size_t)(k - 9) * SLOT, Wc, nullptr, oc, 256 };
                }
                ca.d[s] = { oh, oc,
                            W_hh + (size_t)k * 4 * HID * HID,
                            W_ih + (size_t)k * 4 * HID,
                            b_ih + (size_t)k * 4 * HID,
                            b_hh + (size_t)k * 4 * HID,
                            x + i * 9 + j,
                            gh + (size_t)k * SLOT,
                            gc + (size_t)k * SLOT };
            }
            projseg_kernel<<<dim3(8, 2, nb), 256, 0, stream>>>(base);
            projseg_kernel<<<dim3(8, 2, ni), 256, 0, stream>>>(inc);
            cell_kernel<<<dim3(8, 8, nc), 256, 0, stream>>>(ca);
        }
    }
    final_kernel<<<dim3(64), 256, 0, stream>>>(
        gh + (size_t)80 * SLOT, gc + (size_t)80 * SLOT,
        W_out, b_out, out, fh, fc);
}

// Round 9
// 1151.179 us; speedup vs baseline: 1.8081x; 1.8081x over previous
//
#include <hip/hip_runtime.h>
#include <math.h>

#define BATCH 1024
#define HID 256
#define W3 768
#define SLOT (BATCH * HID)

typedef __bf16 bf16_t;
typedef __bf16 bf16x8 __attribute__((ext_vector_type(8)));
typedef __bf16 bf16x4 __attribute__((ext_vector_type(4)));
typedef float f32x4 __attribute__((ext_vector_type(4)));

__device__ inline bf16x8 cvt8(const float4 a, const float4 b) {
    bf16x8 r;
    r[0] = (bf16_t)a.x; r[1] = (bf16_t)a.y; r[2] = (bf16_t)a.z; r[3] = (bf16_t)a.w;
    r[4] = (bf16_t)b.x; r[5] = (bf16_t)b.y; r[6] = (bf16_t)b.z; r[7] = (bf16_t)b.w;
    return r;
}
__device__ inline bf16x4 cvt4(const float4 a) {
    bf16x4 r;
    r[0] = (bf16_t)a.x; r[1] = (bf16_t)a.y; r[2] = (bf16_t)a.z; r[3] = (bf16_t)a.w;
    return r;
}

// bijective XCD swizzle (m204)
__device__ inline int swz_work(int bid, int N) {
    const int xcd = bid & 7, idx = bid >> 3;
    const int q = N >> 3, r = N & 7;
    return (xcd < r ? xcd * (q + 1) : r * (q + 1) + (xcd - r) * q) + idx;
}

// ---------- P0a: Wcpb = bf16(W_cp) ----------
__global__ __launch_bounds__(256) void wcp_conv(
        const float* __restrict__ wcp, bf16_t* __restrict__ wcpb) {
    const size_t n4 = (size_t)81 * HID * W3 / 4;
    size_t i = (size_t)blockIdx.x * 256 + threadIdx.x;
    const size_t nth = (size_t)gridDim.x * 256;
    for (; i < n4; i += nth) {
        const float4 v = *(const float4*)(wcp + i * 4);
        *(bf16x4*)(wcpb + i * 4) = cvt4(v);
    }
}

// ---------- P0b: WhpT[k][m][u] = bf16(W_hp[k][u][m]) ----------
__global__ __launch_bounds__(256) void whp_t_kernel(
        const float* __restrict__ whp, bf16_t* __restrict__ whpT) {
    const int k = blockIdx.z;
    const int m0 = blockIdx.x * 64, u0 = blockIdx.y * 64;
    const int t = threadIdx.x;
    const int tm = t & 63, tg = t >> 6;
    const float* src = whp + (size_t)k * HID * W3;
    bf16_t* dst = whpT + (size_t)k * W3 * HID;
    #pragma unroll
    for (int c = 0; c < 2; ++c) {
        const int ub = u0 + (tg + c * 4) * 8;
        bf16x8 v;
        #pragma unroll
        for (int i = 0; i < 8; ++i)
            v[i] = (bf16_t)src[(size_t)(ub + i) * W3 + m0 + tm];
        *(bf16x8*)(dst + (size_t)(m0 + tm) * HID + ub) = v;
    }
}

// ---------- P1: gvec[k][n4] = Whh[k][n4]·b_hp[k] + b_ih + b_hh ----------
__global__ __launch_bounds__(256) void gvec_kernel(
        const float* __restrict__ Whh, const float* __restrict__ bhp,
        const float* __restrict__ bih, const float* __restrict__ bhh,
        float* __restrict__ gvec) {
    const int k = blockIdx.x, t = threadIdx.x;
    __shared__ float bsm[HID];
    bsm[t] = bhp[(size_t)k * HID + t];
    __syncthreads();
    #pragma unroll
    for (int g = 0; g < 4; ++g) {
        const int n4 = g * HID + t;
        const float* wr = Whh + (size_t)k * 4 * HID * HID + (size_t)n4 * HID;
        float s = 0.f;
        for (int u = 0; u < HID; u += 4) {
            const float4 w = *(const float4*)(wr + u);
            s += w.x * bsm[u] + w.y * bsm[u + 1] + w.z * bsm[u + 2] + w.w * bsm[u + 3];
        }
        gvec[(size_t)k * 1024 + n4] = s + bih[(size_t)k * 1024 + n4]
                                        + bhh[(size_t)k * 1024 + n4];
    }
}

// ---------- P2: CC[k][c][m] = perm(Whh)[c]·WhpT[m]  (LDS-staged) ----------
// Operand roles swapped: A=WhpT m-rows, B=Whh c-rows -> D rows = m (contig
// bf16x4 stores), D cols = c.  c = by*128 + g*32 + du <-> n4 = g*256+by*32+du
__global__ __launch_bounds__(256) void compose_kernel(
        const float* __restrict__ Whh, const bf16_t* __restrict__ WhpT,
        bf16_t* __restrict__ CC) {
    __shared__ bf16_t As[128][40];   // c-rows (perm Whh), k=u
    __shared__ bf16_t Bs[128][40];   // m-rows (WhpT), k=u
    const int work = swz_work(blockIdx.x, gridDim.x);
    const int k = work / 48, inner = work % 48;
    const int mt = inner % 6, by = inner / 6;
    const int m0 = mt * 128;
    const int t = threadIdx.x;
    const int lane = t & 63, wid = t >> 6;
    const int wm = wid & 1, wn = wid >> 1;
    const int ln = lane & 15, lh = lane >> 4;
    const int sr = t >> 1, sq = (t & 1) * 16;
    const int g_r = sr >> 5, du_r = sr & 31;
    const float* arow = Whh + (size_t)k * 1024 * HID
                        + (size_t)(g_r * HID + by * 32 + du_r) * HID + sq;
    const bf16_t* brow = WhpT + (size_t)k * W3 * HID + (size_t)(m0 + sr) * HID + sq;

    f32x4 acc[4][4] = {};
    for (int kb = 0; kb < 8; ++kb) {
        const float4 a0 = *(const float4*)(arow + kb * 32);
        const float4 a1 = *(const float4*)(arow + kb * 32 + 4);
        const float4 a2 = *(const float4*)(arow + kb * 32 + 8);
        const float4 a3 = *(const float4*)(arow + kb * 32 + 12);
        const bf16x8 bv0 = *(const bf16x8*)(brow + kb * 32);
        const bf16x8 bv1 = *(const bf16x8*)(brow + kb * 32 + 8);
        const bf16x8 av0 = cvt8(a0, a1), av1 = cvt8(a2, a3);
        __syncthreads();
        *(bf16x8*)&As[sr][sq] = av0;
        *(bf16x8*)&As[sr][sq + 8] = av1;
        *(bf16x8*)&Bs[sr][sq] = bv0;
        *(bf16x8*)&Bs[sr][sq + 8] = bv1;
        __syncthreads();
        bf16x8 af[4], bfv[4];
        #pragma unroll
        for (int mf = 0; mf < 4; ++mf)
            af[mf] = *(const bf16x8*)&Bs[wm * 64 + mf * 16 + ln][lh * 8];
        #pragma unroll
        for (int cf = 0; cf < 4; ++cf)
            bfv[cf] = *(const bf16x8*)&As[wn * 64 + cf * 16 + ln][lh * 8];
        #pragma unroll
        for (int mf = 0; mf < 4; ++mf)
            #pragma unroll
            for (int cf = 0; cf < 4; ++cf)
                acc[mf][cf] = __builtin_amdgcn_mfma_f32_16x16x32_bf16(
                    af[mf], bfv[cf], acc[mf][cf], 0, 0, 0);
    }
    bf16_t* outp = CC + (size_t)k * 1024 * W3;
    #pragma unroll
    for (int cf = 0; cf < 4; ++cf) {
        const int c = by * 128 + wn * 64 + cf * 16 + ln;
        #pragma unroll
        for (int mf = 0; mf < 4; ++mf) {
            const int m = m0 + wm * 64 + mf * 16 + lh * 4;
            bf16x4 v;
            #pragma unroll
            for (int r = 0; r < 4; ++r) v[r] = (bf16_t)acc[mf][cf][r];
            *(bf16x4*)(outp + (size_t)c * W3 + m) = v;
        }
    }
}

// ---------- P3: prevgates (LDS-staged, thread-major vectorized out) ------
__global__ __launch_bounds__(256) void prevgates_kernel(
        const float* __restrict__ gridh, const float* __restrict__ gridc,
        const bf16_t* __restrict__ CC, const bf16_t* __restrict__ Wcpb,
        const float* __restrict__ gvec, const float* __restrict__ Wih,
        const float* __restrict__ bcp, const float* __restrict__ x,
        bf16_t* __restrict__ GP, bf16_t* __restrict__ PP) {
    __shared__ bf16_t A1[128][40];
    __shared__ bf16_t A2[128][40];
    __shared__ bf16_t B1[128][40];
    __shared__ bf16_t B2[32][40];
    const int work = swz_work(blockIdx.x, gridDim.x);
    const int k = work >> 6, inner = work & 63;
    const int bx = inner & 7, by = inner >> 3;
    const int t = threadIdx.x;
    const int lane = t & 63, wid = t >> 6;
    const int wm = wid & 1, wn = wid >> 1;
    const int ln = lane & 15, lh = lane >> 4;
    const int b0 = bx * 128, u0 = by * 32;
    const int sr = t >> 1, sq = (t & 1) * 16;
    const int du2 = t >> 3, kk4 = (t & 7) * 4;

    const float* ha = gridh + (size_t)k * SLOT + (size_t)(b0 + sr) * HID + sq;
    const float* ca = gridc + (size_t)k * SLOT + (size_t)(b0 + sr) * HID + sq;
    const bf16_t* b1r = CC + (size_t)k * 1024 * W3 + (size_t)(by * 128 + sr) * W3 + 512 + sq;
    const bf16_t* b2r = Wcpb + (size_t)k * HID * W3 + (size_t)(u0 + du2) * W3 + 512 + kk4;

    f32x4 accg[4][4] = {};
    f32x4 accp[4] = {};
    for (int kb = 0; kb < 8; ++kb) {
        const float4 h0 = *(const float4*)(ha + kb * 32);
        const float4 h1 = *(const float4*)(ha + kb * 32 + 4);
        const float4 h2 = *(const float4*)(ha + kb * 32 + 8);
        const float4 h3 = *(const float4*)(ha + kb * 32 + 12);
        const float4 c0 = *(const float4*)(ca + kb * 32);
        const float4 c1 = *(const float4*)(ca + kb * 32 + 4);
        const float4 c2 = *(const float4*)(ca + kb * 32 + 8);
        const float4 c3 = *(const float4*)(ca + kb * 32 + 12);
        const bf16x8 w0 = *(const bf16x8*)(b1r + kb * 32);
        const bf16x8 w1 = *(const bf16x8*)(b1r + kb * 32 + 8);
        const bf16x4 p0 = *(const bf16x4*)(b2r + kb * 32);
        const bf16x8 hv0 = cvt8(h0, h1), hv1 = cvt8(h2, h3);
        const bf16x8 cv0 = cvt8(c0, c1), cv1 = cvt8(c2, c3);
        __syncthreads();
        *(bf16x8*)&A1[sr][sq] = hv0;  *(bf16x8*)&A1[sr][sq + 8] = hv1;
        *(bf16x8*)&A2[sr][sq] = cv0;  *(bf16x8*)&A2[sr][sq + 8] = cv1;
        *(bf16x8*)&B1[sr][sq] = w0;   *(bf16x8*)&B1[sr][sq + 8] = w1;
        *(bf16x4*)&B2[du2][kk4] = p0;
        __syncthreads();
        bf16x8 af1[4], af2[4], bf1[4], bf2;
        #pragma unroll
        for (int mf = 0; mf < 4; ++mf) {
            af1[mf] = *(const bf16x8*)&A1[wm * 64 + mf * 16 + ln][lh * 8];
            af2[mf] = *(const bf16x8*)&A2[wm * 64 + mf * 16 + ln][lh * 8];
        }
        #pragma unroll
        for (int g = 0; g < 4; ++g)
            bf1[g] = *(const bf16x8*)&B1[g * 32 + wn * 16 + ln][lh * 8];
        bf2 = *(const bf16x8*)&B2[wn * 16 + ln][lh * 8];
        #pragma unroll
        for (int mf = 0; mf < 4; ++mf) {
            #pragma unroll
            for (int g = 0; g < 4; ++g)
                accg[mf][g] = __builtin_amdgcn_mfma_f32_16x16x32_bf16(
                    af1[mf], bf1[g], accg[mf][g], 0, 0, 0);
            accp[mf] = __builtin_amdgcn_mfma_f32_16x16x32_bf16(
                af2[mf], bf2, accp[mf], 0, 0, 0);
        }
    }

    const int u = u0 + wn * 16 + ln;
    float wv[4], gv[4];
    #pragma unroll
    for (int g = 0; g < 4; ++g) {
        const int n4 = g * HID + u;
        wv[g] = Wih[(size_t)k * 1024 + n4];
        gv[g] = gvec[(size_t)k * 1024 + n4];
    }
    const float bc = bcp[(size_t)k * HID + u];
    const int blk = by * 8 + bx;
    bf16_t* gpb = GP + (size_t)k * (BATCH * 1024) + (size_t)blk * 16384;
    bf16_t* ppb = PP + (size_t)k * SLOT + (size_t)blk * 4096;
    #pragma unroll
    for (int mf = 0; mf < 4; ++mf) {
        #pragma unroll
        for (int rp = 0; rp < 2; ++rp) {
            bf16x8 v;
            #pragma unroll
            for (int a = 0; a < 2; ++a) {
                const int r = rp * 2 + a;
                const int b = b0 + wm * 64 + mf * 16 + lh * 4 + r;
                const float xv = x[(size_t)b * 81 + k];
                #pragma unroll
                for (int g = 0; g < 4; ++g)
                    v[a * 4 + g] = (bf16_t)(accg[mf][g][r] + gv[g] + xv * wv[g]);
            }
            *(bf16x8*)(gpb + (size_t)(mf * 2 + rp) * 2048 + t * 8) = v;
        }
    }
    #pragma unroll
    for (int j = 0; j < 2; ++j) {
        bf16x8 v;
        #pragma unroll
        for (int h2 = 0; h2 < 2; ++h2) {
            const int mf = j * 2 + h2;
            #pragma unroll
            for (int r = 0; r < 4; ++r)
                v[h2 * 4 + r] = (bf16_t)(accp[mf][r] + bc);
        }
        *(bf16x8*)(ppb + (size_t)j * 2048 + t * 8) = v;
    }
}

// ---------- serial wavefront stage (LDS-staged, vector GP/PP) ----------
struct Stage2Desc {
    const float* hs0; const float* cs0;   // left (ko=0) or null
    const float* hs1; const float* cs1;   // up (ko=256) or null
    const bf16_t* cc; const bf16_t* wcpb;
    const bf16_t* gp; const bf16_t* pp;
    float* gh; float* gc;
};
struct Stage2Args { Stage2Desc d[9]; };

__global__ __launch_bounds__(256) void stage2_kernel(Stage2Args args) {
    __shared__ bf16_t A1[128][40];
    __shared__ bf16_t A2[128][40];
    __shared__ bf16_t B1[128][40];
    __shared__ bf16_t B2[32][40];
    const int work = swz_work(blockIdx.x, gridDim.x);
    const int cell = work >> 6, inner = work & 63;
    const Stage2Desc sd = args.d[cell];
    const int bx = inner & 7, by = inner >> 3;
    const int t = threadIdx.x;
    const int lane = t & 63, wid = t >> 6;
    const int wm = wid & 1, wn = wid >> 1;
    const int ln = lane & 15, lh = lane >> 4;
    const int b0 = bx * 128, u0 = by * 32;
    const int sr = t >> 1, sq = (t & 1) * 16;
    const int du2 = t >> 3, kk4 = (t & 7) * 4;

    // hoisted GP/PP loads (independent of GEMM; latency hides under K-loop)
    const int blk = by * 8 + bx;
    const bf16_t* gpb = sd.gp + (size_t)blk * 16384;
    const bf16_t* ppb = sd.pp + (size_t)blk * 4096;
    bf16x8 gpv[8], ppv[2];
    #pragma unroll
    for (int e = 0; e < 8; ++e)
        gpv[e] = *(const bf16x8*)(gpb + (size_t)e * 2048 + t * 8);
    #pragma unroll
    for (int j = 0; j < 2; ++j)
        ppv[j] = *(const bf16x8*)(ppb + (size_t)j * 2048 + t * 8);

    f32x4 accg[4][4] = {};
    f32x4 accp[4] = {};
    const float* hseg[2] = { sd.hs0, sd.hs1 };
    const float* cseg[2] = { sd.cs0, sd.cs1 };

    for (int s = 0; s < 2; ++s) {
        const float* hp = hseg[s];
        if (!hp) continue;
        const float* cp = cseg[s];
        const int ko = s * 256;
        const float* ha = hp + (size_t)(b0 + sr) * HID + sq;
        const float* ca = cp + (size_t)(b0 + sr) * HID + sq;
        const bf16_t* b1r = sd.cc + (size_t)(by * 128 + sr) * W3 + ko + sq;
        const bf16_t* b2r = sd.wcpb + (size_t)(u0 + du2) * W3 + ko + kk4;
        for (int kb = 0; kb < 8; ++kb) {
            const float4 h0 = *(const float4*)(ha + kb * 32);
            const float4 h1 = *(const float4*)(ha + kb * 32 + 4);
            const float4 h2 = *(const float4*)(ha + kb * 32 + 8);
            const float4 h3 = *(const float4*)(ha + kb * 32 + 12);
            const float4 c0 = *(const float4*)(ca + kb * 32);
            const float4 c1 = *(const float4*)(ca + kb * 32 + 4);
            const float4 c2 = *(const float4*)(ca + kb * 32 + 8);
            const float4 c3 = *(const float4*)(ca + kb * 32 + 12);
            const bf16x8 w0 = *(const bf16x8*)(b1r + kb * 32);
            const bf16x8 w1 = *(const bf16x8*)(b1r + kb * 32 + 8);
            const bf16x4 p0 = *(const bf16x4*)(b2r + kb * 32);
            const bf16x8 hv0 = cvt8(h0, h1), hv1 = cvt8(h2, h3);
            const bf16x8 cv0 = cvt8(c0, c1), cv1 = cvt8(c2, c3);
            __syncthreads();
            *(bf16x8*)&A1[sr][sq] = hv0;  *(bf16x8*)&A1[sr][sq + 8] = hv1;
            *(bf16x8*)&A2[sr][sq] = cv0;  *(bf16x8*)&A2[sr][sq + 8] = cv1;
            *(bf16x8*)&B1[sr][sq] = w0;   *(bf16x8*)&B1[sr][sq + 8] = w1;
            *(bf16x4*)&B2[du2][kk4] = p0;
            __syncthreads();
            bf16x8 af1[4], af2[4], bf1[4], bf2;
            #pragma unroll
            for (int mf = 0; mf < 4; ++mf) {
                af1[mf] = *(const bf16x8*)&A1[wm * 64 + mf * 16 + ln][lh * 8];
                af2[mf] = *(const bf16x8*)&A2[wm * 64 + mf * 16 + ln][lh * 8];
            }
            #pragma unroll
            for (int g = 0; g < 4; ++g)
                bf1[g] = *(const bf16x8*)&B1[g * 32 + wn * 16 + ln][lh * 8];
            bf2 = *(const bf16x8*)&B2[wn * 16 + ln][lh * 8];
            #pragma unroll
            for (int mf = 0; mf < 4; ++mf) {
                #pragma unroll
                for (int g = 0; g < 4; ++g)
                    accg[mf][g] = __builtin_amdgcn_mfma_f32_16x16x32_bf16(
                        af1[mf], bf1[g], accg[mf][g], 0, 0, 0);
                accp[mf] = __builtin_amdgcn_mfma_f32_16x16x32_bf16(
                    af2[mf], bf2, accp[mf], 0, 0, 0);
            }
        }
    }

    const int u = u0 + wn * 16 + ln;
    float pcv[4][4];
    #pragma unroll
    for (int j = 0; j < 2; ++j)
        #pragma unroll
        for (int h2 = 0; h2 < 2; ++h2)
            #pragma unroll
            for (int r = 0; r < 4; ++r)
                pcv[j * 2 + h2][r] = accp[j * 2 + h2][r] + (float)ppv[j][h2 * 4 + r];
    #pragma unroll
    for (int mf = 0; mf < 4; ++mf) {
        #pragma unroll
        for (int rp = 0; rp < 2; ++rp) {
            const bf16x8 v = gpv[mf * 2 + rp];
            #pragma unroll
            for (int a = 0; a < 2; ++a) {
                const int r = rp * 2 + a;
                const int b = b0 + wm * 64 + mf * 16 + lh * 4 + r;
                const float gi = accg[mf][0][r] + (float)v[a * 4 + 0];
                const float gf = accg[mf][1][r] + (float)v[a * 4 + 1];
                const float gg = accg[mf][2][r] + (float)v[a * 4 + 2];
                const float go = accg[mf][3][r] + (float)v[a * 4 + 3];
                const float pc = pcv[mf][r];
                const float i_ = 1.f / (1.f + expf(-gi));
                const float f_ = 1.f / (1.f + expf(-gf));
                const float o_ = 1.f / (1.f + expf(-go));
                const float g_ = tanhf(gg);
                const float cn = f_ * pc + i_ * g_;
                const float hn = o_ * tanhf(cn);
                sd.gh[(size_t)b * HID + u] = hn;
                sd.gc[(size_t)b * HID + u] = cn;
            }
        }
    }
}

__global__ __launch_bounds__(256) void final_kernel(
        const float* __restrict__ gh88, const float* __restrict__ gc88,
        const float* __restrict__ Wout, const float* __restrict__ bout,
        float* __restrict__ out, float* __restrict__ fh, float* __restrict__ fc) {
    const int tid = blockIdx.x * blockDim.x + threadIdx.x;
    const int nth = gridDim.x * blockDim.x;
    for (int idx = tid; idx < BATCH * HID; idx += nth) {
        fh[idx] = gh88[idx];
        fc[idx] = gc88[idx];
    }
    if (tid < BATCH) {
        float s = bout[0];
        for (int k = 0; k < HID; ++k) s += gh88[(size_t)tid * HID + k] * Wout[k];
        s = fmaxf(s, 0.f);
        out[tid] = 1.f / (1.f + expf(-s));
    }
}

// ---------- fallback (small ws): two-phase wavefront ----------
template<bool ATOMIC>
__device__ __forceinline__ void proj_core(
        const float* __restrict__ src, const float* __restrict__ W, int koff,
        const float* __restrict__ bias, float* __restrict__ out,
        bf16_t (*Asm)[40], bf16_t (*Bsm)[40]) {
    const int t = threadIdx.x;
    const int lane = t & 63, wid = t >> 6;
    const int wm = wid & 1, wn = wid >> 1;
    const int ln = lane & 15, lh = lane >> 4;
    const int b0 = blockIdx.x * 128, n0 = blockIdx.y * 128;
    const int sr = t >> 1, sq = (t & 1) * 16;
    const float* arow = src + (size_t)(b0 + sr) * HID + sq;
    const float* wrow = W + (size_t)(n0 + sr) * W3 + koff + sq;
    f32x4 acc[4][4] = {};
    for (int kb = 0; kb < 8; ++kb) {
        const float4 a0 = *(const float4*)(arow + kb * 32);
        const float4 a1 = *(const float4*)(arow + kb * 32 + 4);
        const float4 a2 = *(const float4*)(arow + kb * 32 + 8);
        const float4 a3 = *(const float4*)(arow + kb * 32 + 12);
        const float4 w0 = *(const float4*)(wrow + kb * 32);
        const float4 w1 = *(const float4*)(wrow + kb * 32 + 4);
        const float4 w2 = *(const float4*)(wrow + kb * 32 + 8);
        const float4 w3 = *(const float4*)(wrow + kb * 32 + 12);
        const bf16x8 av0 = cvt8(a0, a1), av1 = cvt8(a2, a3);
        const bf16x8 bv0 = cvt8(w0, w1), bv1 = cvt8(w2, w3);
        __syncthreads();
        *(bf16x8*)&Asm[sr][sq] = av0;
        *(bf16x8*)&Asm[sr][sq + 8] = av1;
        *(bf16x8*)&Bsm[sr][sq] = bv0;
        *(bf16x8*)&Bsm[sr][sq + 8] = bv1;
        __syncthreads();
        bf16x8 af[4], bfv[4];
        #pragma unroll
        for (int mf = 0; mf < 4; ++mf)
            af[mf] = *(const bf16x8*)&Asm[wm * 64 + mf * 16 + ln][lh * 8];
        #pragma unroll
        for (int nf = 0; nf < 4; ++nf)
            bfv[nf] = *(const bf16x8*)&Bsm[wn * 64 + nf * 16 + ln][lh * 8];
        #pragma unroll
        for (int mf = 0; mf < 4; ++mf)
            #pragma unroll
            for (int nf = 0; nf < 4; ++nf)
                acc[mf][nf] = __builtin_amdgcn_mfma_f32_16x16x32_bf16(
                    af[mf], bfv[nf], acc[mf][nf], 0, 0, 0);
    }
    #pragma unroll
    for (int nf = 0; nf < 4; ++nf) {
        const int n = n0 + wn * 64 + nf * 16 + ln;
        const float bn = ATOMIC ? 0.f : bias[n];
        #pragma unroll
        for (int mf = 0; mf < 4; ++mf)
            #pragma unroll
            for (int r = 0; r < 4; ++r) {
                const int b = b0 + wm * 64 + mf * 16 + lh * 4 + r;
                if (ATOMIC)
                    unsafeAtomicAdd(out + (size_t)b * HID + n, acc[mf][nf][r]);
                else
                    out[(size_t)b * HID + n] = acc[mf][nf][r] + bn;
            }
    }
}

struct SegDesc { const float* src; const float* W; const float* bias; float* out; int koff; };
struct SegArgs { SegDesc d[36]; };

__global__ __launch_bounds__(256) void projseg_kernel(SegArgs a) {
    __shared__ bf16_t As[128][40];
    __shared__ bf16_t Bs[128][40];
    const SegDesc d = a.d[blockIdx.z];
    if (d.bias) proj_core<false>(d.src, d.W, d.koff, d.bias, d.out, As, Bs);
    else        proj_core<true>(d.src, d.W, d.koff, nullptr, d.out, As, Bs);
}

struct CellDesc {
    const float* ph; const float* pc;
    const float* Whh; const float* Wih; const float* bih; const float* bhh;
    const float* xcol;
    float* gh; float* gc;
};
struct CellBatchArgs { CellDesc d[9]; };

__global__ __launch_bounds__(256) void cell_kernel(CellBatchArgs args) {
    const CellDesc cd = args.d[blockIdx.z];
    __shared__ bf16_t Psm[128][40];
    __shared__ bf16_t Wsm[128][40];
    const int t = threadIdx.x;
    const int lane = t & 63, wid = t >> 6;
    const int wm = wid & 1, wn = wid >> 1;
    const int ln = lane & 15, lh = lane >> 4;
    const int b0 = blockIdx.x * 128;
    const int u0 = blockIdx.y * 32;
    const int sr = t >> 1, sq = (t & 1) * 16;
    const float* prow = cd.ph + (size_t)(b0 + sr) * HID + sq;
    const int cg = sr >> 5, cdu = sr & 31;
    const float* wrow = cd.Whh + (size_t)(cg * HID + u0 + cdu) * HID + sq;
    f32x4 acc[4][4] = {};
    for (int kb = 0; kb < 8; ++kb) {
        const float4 p0 = *(const float4*)(prow + kb * 32);
        const float4 p1 = *(const float4*)(prow + kb * 32 + 4);
        const float4 p2 = *(const float4*)(prow + kb * 32 + 8);
        const float4 p3 = *(const float4*)(prow + kb * 32 + 12);
        const float4 w0 = *(const float4*)(wrow + kb * 32);
        const float4 w1 = *(const float4*)(wrow + kb * 32 + 4);
        const float4 w2 = *(const float4*)(wrow + kb * 32 + 8);
        const float4 w3 = *(const float4*)(wrow + kb * 32 + 12);
        const bf16x8 pv0 = cvt8(p0, p1), pv1 = cvt8(p2, p3);
        const bf16x8 wv0 = cvt8(w0, w1), wv1 = cvt8(w2, w3);
        __syncthreads();
        *(bf16x8*)&Psm[sr][sq] = pv0;
        *(bf16x8*)&Psm[sr][sq + 8] = pv1;
        *(bf16x8*)&Wsm[sr][sq] = wv0;
        *(bf16x8*)&Wsm[sr][sq + 8] = wv1;
        __syncthreads();
        bf16x8 af[4], bfr[4];
        #pragma unroll
        for (int mf = 0; mf < 4; ++mf)
            af[mf] = *(const bf16x8*)&Psm[wm * 64 + mf * 16 + ln][lh * 8];
        #pragma unroll
        for (int g = 0; g < 4; ++g)
            bfr[g] = *(const bf16x8*)&Wsm[g * 32 + wn * 16 + ln][lh * 8];
        #pragma unroll
        for (int mf = 0; mf < 4; ++mf)
            #pragma unroll
            for (int g = 0; g < 4; ++g)
                acc[mf][g] = __builtin_amdgcn_mfma_f32_16x16x32_bf16(
                    af[mf], bfr[g], acc[mf][g], 0, 0, 0);
    }
    const int u = u0 + wn * 16 + ln;
    float wih[4], bsum[4];
    #pragma unroll
    for (int g = 0; g < 4; ++g) {
        const int n = g * HID + u;
        wih[g] = cd.Wih[n];
        bsum[g] = cd.bih[n] + cd.bhh[n];
    }
    #pragma unroll
    for (int mf = 0; mf < 4; ++mf)
        #pragma unroll
        for (int r = 0; r < 4; ++r) {
            const int b = b0 + wm * 64 + mf * 16 + lh * 4 + r;
            const float xv = cd.xcol[(size_t)b * 81];
            const float gi = acc[mf][0][r] + xv * wih[0] + bsum[0];
            const float gf = acc[mf][1][r] + xv * wih[1] + bsum[1];
            const float gg = acc[mf][2][r] + xv * wih[2] + bsum[2];
            const float go = acc[mf][3][r] + xv * wih[3] + bsum[3];
            const float i_ = 1.f / (1.f + expf(-gi));
            const float f_ = 1.f / (1.f + expf(-gf));
            const float o_ = 1.f / (1.f + expf(-go));
            const float g_ = tanhf(gg);
            const float c0 = cd.pc[(size_t)b * HID + u];
            const float cn = f_ * c0 + i_ * g_;
            const float hn = o_ * tanhf(cn);
            cd.gh[(size_t)b * HID + u] = hn;
            cd.gc[(size_t)b * HID + u] = cn;
        }
}

extern "C" void kernel_launch(void* const* d_in, const int* in_sizes, int n_in,
                              void* d_out, int out_size, void* d_ws, size_t ws_size,
                              hipStream_t stream) {
    const float* x      = (const float*)d_in[0];
    const float* h_ext  = (const float*)d_in[1];
    const float* c_ext  = (const float*)d_in[2];
    const float* grid_h = (const float*)d_in[3];
    const float* grid_c = (const float*)d_in[4];
    const float* W_hp   = (const float*)d_in[5];
    const float* b_hp   = (const float*)d_in[6];
    const float* W_cp   = (const float*)d_in[7];
    const float* b_cp   = (const float*)d_in[8];
    const float* W_ih   = (const float*)d_in[9];
    const float* W_hh   = (const float*)d_in[10];
    const float* b_ih   = (const float*)d_in[11];
    const float* b_hh   = (const float*)d_in[12];
    const float* W_out  = (const float*)d_in[13];
    const float* b_out  = (const float*)d_in[14];

    float* out = (float*)d_out;
    float* fh  = out + BATCH * 1;
    float* fc  = fh + SLOT;
    float* gh  = fc + SLOT;
    float* gc  = gh + (size_t)81 * SLOT;

    const size_t wt_b  = (size_t)81 * W3 * HID * 2;
    const size_t wcp_b = (size_t)81 * HID * W3 * 2;
    const size_t cc_b  = (size_t)81 * 1024 * W3 * 2;
    const size_t gp_b  = (size_t)81 * BATCH * 1024 * 2;
    const size_t pp_b  = (size_t)81 * SLOT * 2;
    const size_t gv_b  = (size_t)81 * 1024 * 4;
    const size_t need = wt_b + wcp_b + cc_b + gp_b + pp_b + gv_b;

    if (ws_size >= need) {
        char* p = (char*)d_ws;
        bf16_t* WhpT = (bf16_t*)p; p += wt_b;
        bf16_t* Wcpb = (bf16_t*)p; p += wcp_b;
        bf16_t* CC   = (bf16_t*)p; p += cc_b;
        bf16_t* GP   = (bf16_t*)p; p += gp_b;
        bf16_t* PP   = (bf16_t*)p; p += pp_b;
        float*  gvec = (float*)p;

        wcp_conv<<<dim3(2048), 256, 0, stream>>>(W_cp, Wcpb);
        whp_t_kernel<<<dim3(12, 4, 81), 256, 0, stream>>>(W_hp, WhpT);
        gvec_kernel<<<dim3(81), 256, 0, stream>>>(W_hh, b_hp, b_ih, b_hh, gvec);
        compose_kernel<<<dim3(81 * 48), 256, 0, stream>>>(W_hh, WhpT, CC);
        prevgates_kernel<<<dim3(81 * 64), 256, 0, stream>>>(
            grid_h, grid_c, CC, Wcpb, gvec, W_ih, b_cp, x, GP, PP);

        for (int d = 0; d <= 16; ++d) {
            const int i_lo = d > 8 ? d - 8 : 0;
            const int i_hi = d < 8 ? d : 8;
            const int nc = i_hi - i_lo + 1;
            Stage2Args sa{};
            for (int s = 0; s < nc; ++s) {
                const int i = i_lo + s, j = d - i;
                const int k = i * 9 + j;
                const float *hl = nullptr, *cl = nullptr, *hu = nullptr, *cu = nullptr;
                if (i == 0 && j == 0)      { hl = h_ext; cl = c_ext; }
                else if (j > 0)            { hl = gh + (size_t)(k - 1) * SLOT;
                                             cl = gc + (size_t)(k - 1) * SLOT; }
                if (i > 0)                 { hu = gh + (size_t)(k - 9) * SLOT;
                                             cu = gc + (size_t)(k - 9) * SLOT; }
                sa.d[s] = { hl, cl, hu, cu,
                            CC + (size_t)k * 1024 * W3,
                            Wcpb + (size_t)k * HID * W3,
                            GP + (size_t)k * BATCH * 1024,
                            PP + (size_t)k * SLOT,
                            gh + (size_t)k * SLOT, gc + (size_t)k * SLOT };
            }
            stage2_kernel<<<dim3(nc * 64), 256, 0, stream>>>(sa);
        }
    } else {
        float* ws = (float*)d_ws;
        for (int d = 0; d <= 16; ++d) {
            const int i_lo = d > 8 ? d - 8 : 0;
            const int i_hi = d < 8 ? d : 8;
            const int nc = i_hi - i_lo + 1;
            SegArgs base{}, inc{};
            CellBatchArgs ca{};
            int nb = 0, ni = 0;
            for (int s = 0; s < nc; ++s) {
                const int i = i_lo + s, j = d - i;
                const int k = i * 9 + j;
                float* oh = ws + (size_t)(2 * s) * SLOT;
                float* oc = oh + SLOT;
                const float* Wh = W_hp + (size_t)k * HID * W3;
                const float* Wc = W_cp + (size_t)k * HID * W3;
                base.d[nb++] = { grid_h + (size_t)k * SLOT, Wh, b_hp + (size_t)k * HID, oh, 512 };
                base.d[nb++] = { grid_c + (size_t)k * SLOT, Wc, b_cp + (size_t)k * HID, oc, 512 };
                if (i == 0 && j == 0) {
                    inc.d[ni++] = { h_ext, Wh, nullptr, oh, 0 };
                    inc.d[ni++] = { c_ext, Wc, nullptr, oc, 0 };
                } else if (j > 0) {
                    inc.d[ni++] = { gh + (size_t)(k - 1) * SLOT, Wh, nullptr, oh, 0 };
                    inc.d[ni++] = { gc + (size_t)(k - 1) * SLOT, Wc, nullptr, oc, 0 };
                }
                if (i > 0) {
                    inc.d[ni++] = { gh + (size_t)(k - 9) * SLOT, Wh, nullptr, oh, 256 };
                    inc.d[ni++] = { gc + (size_t)(k - 9) * SLOT, Wc, nullptr, oc, 256 };
                }
                ca.d[s] = { oh, oc,
                            W_hh + (size_t)k * 4 * HID * HID,
                            W_ih + (size_t)k * 4 * HID,
                            b_ih + (size_t)k * 4 * HID,
                            b_hh + (size_t)k * 4 * HID,
                            x + i * 9 + j,
                            gh + (size_t)k * SLOT,
                            gc + (size_t)k * SLOT };
            }
            projseg_kernel<<<dim3(8, 2, nb), 256, 0, stream>>>(base);
            projseg_kernel<<<dim3(8, 2, ni), 256, 0, stream>>>(inc);
            cell_kernel<<<dim3(8, 8, nc), 256, 0, stream>>>(ca);
        }
    }
    final_kernel<<<dim3(64), 256, 0, stream>>>(
        gh + (size_t)80 * SLOT, gc + (size_t)80 * SLOT,
        W_out, b_out, out, fh, fc);
}